// Round 5
// baseline (225.731 us; speedup 1.0000x reference)
//
#include <hip/hip_runtime.h>

// Problem constants (match reference setup_inputs)
#define BB   64
#define CIN  2048
#define COUT 2048
#define TT   128

// Sparse compaction geometry:
//   pair  = 32 output channels (4 mask row-blocks)  -> 64 pairs
//   slot  = 16 k values (2 mask col-blocks)         -> 128 slots, keep ~0.57
//   window= 32 slots (512 bytes of a row)           -> 4 windows
//   chunk = 4 slots = one MFMA K=64
#define NPAIR 64
#define NWIN  4
#define SLOTW 32

typedef int i32x4 __attribute__((ext_vector_type(4)));

__device__ __forceinline__ void async16(char* lds_dst, const char* g_src) {
    __builtin_amdgcn_global_load_lds(
        (const __attribute__((address_space(1))) void*)g_src,
        (__attribute__((address_space(3))) void*)lds_dst,
        16, 0, 0);
}

// --- prep1: spikes -> i8 A[(b*T+t)][c] via 256ch x 32t LDS transpose tiles
//            + 256 ballot blocks (bid>=2048): keep-bit table kb[256][4] u64
__global__ void prep1(const float* __restrict__ spikes,
                      const float* __restrict__ msk,
                      char* __restrict__ A,
                      unsigned long long* __restrict__ kb) {
    int bid = blockIdx.x;
    int tid = threadIdx.x;

    if (bid >= 2048) {
        int rb = bid - 2048;
        bool keep = (msk[(size_t)(rb * 8) * CIN + tid * 8] != 0.f);
        unsigned long long m = __ballot(keep);
        if ((tid & 63) == 0) kb[rb * 4 + (tid >> 6)] = m;
        return;
    }

    __shared__ float tile[32][256];            // 32 KB
    int cg = bid & 7, tg = (bid >> 3) & 3, b = bid >> 5;
    int c0 = cg * 256, t0 = tg * 32;

    {
        const float* src = spikes + ((size_t)b * CIN + c0 + tid) * TT + t0;
#pragma unroll
        for (int j = 0; j < 8; ++j) {
            float4 v = *(const float4*)(src + j * 4);
            tile[j * 4 + 0][tid] = v.x;
            tile[j * 4 + 1][tid] = v.y;
            tile[j * 4 + 2][tid] = v.z;
            tile[j * 4 + 3][tid] = v.w;
        }
    }
    __syncthreads();

    const int cq = tid & 63, tw = tid >> 6;
#pragma unroll
    for (int s2 = 0; s2 < 8; ++s2) {
        int t = s2 * 4 + tw;
        float4 v = *(const float4*)&tile[t][cq * 4];   // contiguous 1KB/wave
        unsigned pk = (v.x != 0.f ? 0x1u : 0u) | (v.y != 0.f ? 0x100u : 0u) |
                      (v.z != 0.f ? 0x10000u : 0u) | (v.w != 0.f ? 0x1000000u : 0u);
        *(unsigned*)(A + ((size_t)(b * TT) + t0 + t) * CIN + c0 + cq * 4) = pk;
    }
}

// --- prep2: redundant per-block meta (bm/ofs/nch from kb, L2-hot)
//            + fill compacted B (frag-ready [slot][col 0..31][16B]) + slot lists
__global__ void prep2(const float* __restrict__ w,
                      const float* __restrict__ msk,
                      const unsigned long long* __restrict__ kb,
                      char* __restrict__ Bc,
                      unsigned short* __restrict__ lst,
                      unsigned* __restrict__ ofs_g,
                      unsigned* __restrict__ nch_g) {
    __shared__ unsigned sbm[256];
    __shared__ unsigned snch[256];
    __shared__ unsigned sofs[256];
    const int tid = threadIdx.x;
    const int pw_self = blockIdx.x;

    {
        int p = tid >> 2, wdw = tid & 3;
        unsigned long long r = kb[(4 * p + 0) * 4 + wdw] | kb[(4 * p + 1) * 4 + wdw] |
                               kb[(4 * p + 2) * 4 + wdw] | kb[(4 * p + 3) * 4 + wdw];
        unsigned long long t2 = r | (r >> 1);
        unsigned bm = 0u;
#pragma unroll
        for (int s = 0; s < 32; ++s)
            bm |= (unsigned)((t2 >> (2 * s)) & 1ull) << s;
        sbm[tid]  = bm;
        snch[tid] = (unsigned)((__popc(bm) + 3) >> 2);
    }
    __syncthreads();
    if (tid == 0) {
        unsigned run = 0;
#pragma unroll 4
        for (int i = 0; i < 256; ++i) { sofs[i] = run; run += snch[i] * 4; }
        ofs_g[pw_self] = sofs[pw_self];
        nch_g[pw_self] = snch[pw_self];
    }
    __syncthreads();

    const int p = pw_self >> 2, wdw = pw_self & 3;
    unsigned rem = sbm[pw_self];
    const unsigned o = sofs[pw_self];
    const unsigned nslots = snch[pw_self] * 4;

    for (unsigned j = 0; j < nslots; ++j) {
        int kl = 0;
        bool real = false;
        if (rem) { kl = __ffs(rem) - 1; rem &= rem - 1u; real = true; }
        int kk = wdw * SLOTW + kl;
        if (tid < 128) {
            int col = tid >> 2, q = tid & 3;
            unsigned pk = 0u;
            if (real) {
                size_t base = (size_t)(p * 32 + col) * CIN + kk * 16 + q * 4;
                float4 a = *(const float4*)(w + base);
                float4 m = *(const float4*)(msk + base);
                int b0 = (int)(char)(int)(a.x * m.x);
                int b1 = (int)(char)(int)(a.y * m.y);
                int b2 = (int)(char)(int)(a.z * m.z);
                int b3 = (int)(char)(int)(a.w * m.w);
                pk = (unsigned)((b0 & 0xFF) | ((b1 & 0xFF) << 8) | ((b2 & 0xFF) << 16) | (b3 << 24));
            }
            *(unsigned*)(Bc + (size_t)(o + j) * 512 + col * 16 + q * 4) = pk;
        }
        if (tid == 0) lst[o + j] = (unsigned short)(real ? kl : 0);
    }
}

// --- Sparse-gather GEMM: BM=128 (one batch), BN=256 (8 pairs), compacted K
//     XCD = nt (pair-group): 300 KB Bc slice stays L2-resident per XCD
//     + LIF scan epilogue in two 128-channel passes + coalesced store ---
__global__ void __launch_bounds__(512, 4)
snn_gemm_scan(const char* __restrict__ A,     // [8192][2048] i8
              const char* __restrict__ Bc,    // compacted [slot][32][16] i8
              const unsigned short* __restrict__ lst,
              const unsigned* __restrict__ ofs,
              const unsigned* __restrict__ nchv,
              const int* __restrict__ scale_exp,
              const int* __restrict__ thr_exp,
              float* __restrict__ out) {      // [B][COUT][T]
    __shared__ __align__(16) union {
        char a[128 * 512];                    // 64 KB A k-window
        float c[128 * 132];                   // 67.6 KB scan buffer
    } lds;
    __shared__ unsigned short slist[8][NWIN][SLOTW];  // 2 KB, persistent
    __shared__ unsigned smeta_ofs[32];                // [pl*4+w]
    __shared__ unsigned smeta_nch[32];
    __shared__ unsigned pb[128 * 4];

    const int tid  = threadIdx.x;
    const int lane = tid & 63;
    const int w    = tid >> 6;
    const int wr   = w >> 2;    // 0..1: row half (4 m-frags)
    const int wp   = w & 3;     // 0..3: pair-pair (2 pairs each)

    // bid = b*8 + nt: XCD = bid%8 = nt -> each XCD owns ONE pair-group;
    // its 300 KB Bc slice is L2-resident (hot every chunk); A streams once.
    const int bid = blockIdx.x;
    const int nt = bid & 7;           // 0..7 = XCD
    const int b  = bid >> 3;          // 0..63
    const int m0 = b * TT;
    const int p0 = nt * 8;            // global pair base

    const int mrow = lane & 15, kc = lane >> 4;

    // ---- block-persistent meta + slot lists (one-time) ----
    if (tid < 64) {
        int i = tid & 31;             // pl*4 + w
        unsigned g = (p0 + (i >> 2)) * 4 + (i & 3);
        if (tid < 32) smeta_ofs[i] = ofs[g];
        else          smeta_nch[i] = nchv[g];
    }
    {
        int pl = tid >> 6;
        int rest = tid & 63;          // w2*16 + e-pair
        int w2 = rest >> 4, e = (rest & 15) * 2;
        unsigned g = (p0 + pl) * 4 + w2;
        unsigned o = ofs[g];
        *(unsigned*)&slist[pl][w2][e] = *(const unsigned*)(lst + o + e);
    }

    i32x4 acc[4][2][2] = {};          // [m-frag][pair][col-frag]

    for (int wdw = 0; wdw < NWIN; ++wdw) {
        __syncthreads();              // prior window reads done / meta visible
        // stage A window: 128 rows x 512 B, source XOR-swizzled, dest linear
#pragma unroll
        for (int i = 0; i < 8; ++i) {
            int f = i * 512 + tid;
            int row = f >> 5, g0 = f & 31;
            int src = (g0 & ~7) | ((g0 & 7) ^ (row & 7));
            async16((char*)lds.a + (size_t)f * 16,
                    A + (size_t)(m0 + row) * CIN + wdw * 512 + src * 16);
        }
        __syncthreads();              // staging complete (vmcnt+lgkm drain)

#pragma unroll
        for (int pi = 0; pi < 2; ++pi) {
            const int pl = wp * 2 + pi;
            const unsigned o   = smeta_ofs[pl * 4 + wdw];
            const unsigned nch = smeta_nch[pl * 4 + wdw];
            const unsigned short* Lp = &slist[pl][wdw][0];
            if (nch == 0) continue;
            const char* bbase = Bc + (size_t)o * 512 + mrow * 16 + (size_t)kc * 512;

            // distance-1 pipeline: b0 of chunk c+1 prefetched during chunk c
            int   kkN = (int)Lp[kc];
            i32x4 b0N = *(const i32x4*)bbase;
            for (unsigned c = 0; c < nch; ++c) {
                const int   kkC = kkN;
                const i32x4 b0C = b0N;
                i32x4 b1C = *(const i32x4*)(bbase + (size_t)c * 2048 + 256);
                if (c + 1 < nch) {
                    kkN = (int)Lp[(c + 1) * 4 + kc];
                    b0N = *(const i32x4*)(bbase + (size_t)(c + 1) * 2048);
                }
                i32x4 av[4];
#pragma unroll
                for (int mf = 0; mf < 4; ++mf) {
                    int row = wr * 64 + mf * 16 + mrow;
                    av[mf] = *(const i32x4*)((const char*)lds.a +
                                 row * 512 + ((kkC ^ (row & 7)) << 4));
                }
#pragma unroll
                for (int mf = 0; mf < 4; ++mf)
                    acc[mf][pi][0] = __builtin_amdgcn_mfma_i32_16x16x64_i8(
                        av[mf], b0C, acc[mf][pi][0], 0, 0, 0);
#pragma unroll
                for (int mf = 0; mf < 4; ++mf)
                    acc[mf][pi][1] = __builtin_amdgcn_mfma_i32_16x16x64_i8(
                        av[mf], b1C, acc[mf][pi][1], 0, 0, 0);
            }
        }
    }

    // ---- Epilogue: LIF scan, two passes of 128 channels ----
    const float thr = exp2f((float)thr_exp[0]);
#pragma unroll
    for (int P = 0; P < 2; ++P) {
        __syncthreads();
        if ((wp >> 1) == P) {
            const int rb = (lane >> 4) * 4;
            const int cb = lane & 15;
            const int cbase = (wp & 1) * 64;
#pragma unroll
            for (int mf = 0; mf < 4; ++mf)
#pragma unroll
                for (int pi = 0; pi < 2; ++pi)
#pragma unroll
                    for (int cf = 0; cf < 2; ++cf)
#pragma unroll
                        for (int r = 0; r < 4; ++r)
                            lds.c[(wr * 64 + mf * 16 + rb + r) * 132 +
                                  cbase + pi * 32 + cf * 16 + cb] =
                                (float)acc[mf][pi][cf][r];
        }
        __syncthreads();

        if (tid < 128) {
            const float scale = exp2f((float)scale_exp[nt * 256 + P * 128 + tid]);
            float a = 0.f;
#pragma unroll
            for (int q = 0; q < 4; ++q) {
                unsigned bq = 0u;
#pragma unroll 8
                for (int j = 0; j < 32; ++j) {
                    a += lds.c[(q * 32 + j) * 132 + tid] * scale;
                    unsigned sp = (a >= thr) ? 1u : 0u;
                    if (sp) a = 0.f;
                    bq |= sp << j;
                }
                pb[tid * 4 + q] = bq;
            }
        }
        __syncthreads();

        const int t4 = tid & 31, u = tid >> 5;
#pragma unroll
        for (int s2 = 0; s2 < 8; ++s2) {
            int co = s2 * 16 + u;
            unsigned wb  = pb[co * 4 + (t4 >> 3)];
            unsigned nib = (wb >> ((t4 & 7) * 4)) & 0xFu;
            float4 v;
            v.x = (float)(nib & 1u);
            v.y = (float)((nib >> 1) & 1u);
            v.z = (float)((nib >> 2) & 1u);
            v.w = (float)((nib >> 3) & 1u);
            *(float4*)(out + (size_t)(b * COUT + nt * 256 + P * 128 + co) * TT
                       + t4 * 4) = v;
        }
    }
}

extern "C" void kernel_launch(void* const* d_in, const int* in_sizes, int n_in,
                              void* d_out, int out_size, void* d_ws, size_t ws_size,
                              hipStream_t stream) {
    const float* spikes  = (const float*)d_in[0];
    const float* weights = (const float*)d_in[1];
    const float* mask    = (const float*)d_in[2];
    const int*   scale_e = (const int*)d_in[3];
    const int*   thr_e   = (const int*)d_in[4];
    float* out = (float*)d_out;

    char* ws = (char*)d_ws;
    char*               Ai8  = ws;                                     // 16 MB
    char*               Bc   = ws + 16777216;                          // 3.75 MB arena
    unsigned short*     lstp = (unsigned short*)(ws + 20709376);       // 16 KB (incl slack)
    unsigned*           ofsp = (unsigned*)(ws + 20725760);             // 1 KB
    unsigned*           nchp = (unsigned*)(ws + 20726784);             // 1 KB
    unsigned long long* kbp  = (unsigned long long*)(ws + 20727808);   // 8 KB

    prep1<<<2048 + 256, 256, 0, stream>>>(spikes, mask, Ai8, kbp);
    prep2<<<NPAIR * NWIN, 256, 0, stream>>>(weights, mask, kbp, Bc, lstp, ofsp, nchp);
    snn_gemm_scan<<<8 * BB, 512, 0, stream>>>(Ai8, Bc, lstp, ofsp, nchp,
                                              scale_e, thr_e, out);
}

// Round 6
// 209.212 us; speedup vs baseline: 1.0790x; 1.0790x over previous
//
#include <hip/hip_runtime.h>

// Problem constants (match reference setup_inputs)
#define BB   64
#define CIN  2048
#define COUT 2048
#define TT   128

// Sparse compaction geometry:
//   pair  = 32 output channels (4 mask row-blocks)  -> 64 pairs
//   slot  = 16 k values (2 mask col-blocks)         -> 128 slots, keep ~0.57
//   window= 32 slots (512 bytes of a row)           -> 4 windows
//   chunk = 4 slots = one MFMA K=64
#define NPAIR 64
#define NWIN  4
#define SLOTW 32

typedef int i32x4 __attribute__((ext_vector_type(4)));

__device__ __forceinline__ void async16(char* lds_dst, const char* g_src) {
    __builtin_amdgcn_global_load_lds(
        (const __attribute__((address_space(1))) void*)g_src,
        (__attribute__((address_space(3))) void*)lds_dst,
        16, 0, 0);
}

// --- prep1: spikes -> i8 A[(b*T+t)][c] via 256ch x 32t LDS transpose tiles
//            + 256 ballot blocks (bid>=2048): keep-bit table kb[256][4] u64
__global__ void prep1(const float* __restrict__ spikes,
                      const float* __restrict__ msk,
                      char* __restrict__ A,
                      unsigned long long* __restrict__ kb) {
    int bid = blockIdx.x;
    int tid = threadIdx.x;

    if (bid >= 2048) {
        int rb = bid - 2048;
        bool keep = (msk[(size_t)(rb * 8) * CIN + tid * 8] != 0.f);
        unsigned long long m = __ballot(keep);
        if ((tid & 63) == 0) kb[rb * 4 + (tid >> 6)] = m;
        return;
    }

    __shared__ float tile[32][256];            // 32 KB
    int cg = bid & 7, tg = (bid >> 3) & 3, b = bid >> 5;
    int c0 = cg * 256, t0 = tg * 32;

    {
        const float* src = spikes + ((size_t)b * CIN + c0 + tid) * TT + t0;
#pragma unroll
        for (int j = 0; j < 8; ++j) {
            float4 v = *(const float4*)(src + j * 4);
            tile[j * 4 + 0][tid] = v.x;
            tile[j * 4 + 1][tid] = v.y;
            tile[j * 4 + 2][tid] = v.z;
            tile[j * 4 + 3][tid] = v.w;
        }
    }
    __syncthreads();

    const int cq = tid & 63, tw = tid >> 6;
#pragma unroll
    for (int s2 = 0; s2 < 8; ++s2) {
        int t = s2 * 4 + tw;
        float4 v = *(const float4*)&tile[t][cq * 4];   // contiguous 1KB/wave
        unsigned pk = (v.x != 0.f ? 0x1u : 0u) | (v.y != 0.f ? 0x100u : 0u) |
                      (v.z != 0.f ? 0x10000u : 0u) | (v.w != 0.f ? 0x1000000u : 0u);
        *(unsigned*)(A + ((size_t)(b * TT) + t0 + t) * CIN + c0 + cq * 4) = pk;
    }
}

// --- prep2: per-block meta from kb (L2-hot), bit positions precomputed,
//            fill loop 2 slots in flight (independent iterations)
__global__ void prep2(const float* __restrict__ w,
                      const float* __restrict__ msk,
                      const unsigned long long* __restrict__ kb,
                      char* __restrict__ Bc,
                      unsigned short* __restrict__ lst,
                      unsigned* __restrict__ ofs_g,
                      unsigned* __restrict__ nch_g) {
    __shared__ unsigned snch[256];
    __shared__ unsigned sofs[256];
    __shared__ unsigned sbm_self;
    __shared__ short skl[SLOTW];
    const int tid = threadIdx.x;
    const int pw_self = blockIdx.x;

    {
        int p = tid >> 2, wdw = tid & 3;
        unsigned long long r = kb[(4 * p + 0) * 4 + wdw] | kb[(4 * p + 1) * 4 + wdw] |
                               kb[(4 * p + 2) * 4 + wdw] | kb[(4 * p + 3) * 4 + wdw];
        unsigned long long t2 = r | (r >> 1);
        unsigned bm = 0u;
#pragma unroll
        for (int s = 0; s < 32; ++s)
            bm |= (unsigned)((t2 >> (2 * s)) & 1ull) << s;
        if (tid == pw_self) sbm_self = bm;
        snch[tid] = (unsigned)((__popc(bm) + 3) >> 2);
    }
    __syncthreads();
    if (tid == 0) {
        unsigned run = 0;
#pragma unroll 4
        for (int i = 0; i < 256; ++i) { sofs[i] = run; run += snch[i] * 4; }
        ofs_g[pw_self] = sofs[pw_self];
        nch_g[pw_self] = snch[pw_self];
        // extract kept-slot positions (serial VALU, <=32 iters)
        unsigned rem = sbm_self;
        unsigned ns = snch[pw_self] * 4;
        unsigned o0 = sofs[pw_self];
        for (unsigned j = 0; j < ns; ++j) {
            int kl = -1;
            if (rem) { kl = __ffs(rem) - 1; rem &= rem - 1u; }
            skl[j] = (short)kl;
            lst[o0 + j] = (unsigned short)(kl >= 0 ? kl : 0);
        }
    }
    __syncthreads();

    const int p = pw_self >> 2, wdw = pw_self & 3;
    const unsigned o = sofs[pw_self];
    const unsigned nslots = snch[pw_self] * 4;

    const int col = (tid & 127) >> 2, q = tid & 3;
    const unsigned jo = tid >> 7;     // 0 or 1: two slots in flight
    for (unsigned j0 = 0; j0 < nslots; j0 += 2) {
        unsigned j = j0 + jo;
        if (j < nslots) {
            int kl = skl[j];
            unsigned pk = 0u;
            if (kl >= 0) {
                int kk = wdw * SLOTW + kl;
                size_t base = (size_t)(p * 32 + col) * CIN + kk * 16 + q * 4;
                float4 a = *(const float4*)(w + base);
                float4 m = *(const float4*)(msk + base);
                int b0 = (int)(char)(int)(a.x * m.x);
                int b1 = (int)(char)(int)(a.y * m.y);
                int b2 = (int)(char)(int)(a.z * m.z);
                int b3 = (int)(char)(int)(a.w * m.w);
                pk = (unsigned)((b0 & 0xFF) | ((b1 & 0xFF) << 8) | ((b2 & 0xFF) << 16) | (b3 << 24));
            }
            *(unsigned*)(Bc + (size_t)(o + j) * 512 + col * 16 + q * 4) = pk;
        }
    }
}

// --- Sparse-gather GEMM: BM=128 (one batch), BN=256 (8 pairs, 1 pair/wave),
//     double-buffered A windows with counted vmcnt (no drain in loop)
//     + LIF scan epilogue in two 128-channel passes + coalesced store ---
__global__ void __launch_bounds__(512, 2)
snn_gemm_scan(const char* __restrict__ A,     // [8192][2048] i8
              const char* __restrict__ Bc,    // compacted [slot][32][16] i8
              const unsigned short* __restrict__ lst,
              const unsigned* __restrict__ ofs,
              const unsigned* __restrict__ nchv,
              const int* __restrict__ scale_exp,
              const int* __restrict__ thr_exp,
              float* __restrict__ out) {      // [B][COUT][T]
    __shared__ __align__(16) union {
        char a[2][128 * 512];                 // 128 KB dbuf A windows
        float c[128 * 132];                   // 67.6 KB scan buffer
    } lds;
    __shared__ unsigned short slist[8][NWIN][SLOTW];  // 2 KB, persistent
    __shared__ unsigned smeta_ofs[32];                // [pl*4+w]
    __shared__ unsigned smeta_nch[32];
    __shared__ unsigned pb[128 * 4];

    const int tid  = threadIdx.x;
    const int lane = tid & 63;
    const int w    = tid >> 6;        // wave id = pair index 0..7

    // bid = nt*64 + b: XCD = bid%8 = b%8 -> all 8 nt-blocks of one batch
    // co-XCD (A panel fetched once per XCD L2 -- r4's verified-best mapping)
    const int bid = blockIdx.x;
    const int b  = bid & 63;
    const int nt = bid >> 6;          // 0..7
    const int m0 = b * TT;
    const int p0 = nt * 8;            // global pair base

    const int mrow = lane & 15, kc = lane >> 4;

    // ---- block-persistent meta + slot lists (one-time) ----
    if (tid < 64) {
        int i = tid & 31;             // pl*4 + w
        unsigned g = (p0 + (i >> 2)) * 4 + (i & 3);
        if (tid < 32) smeta_ofs[i] = ofs[g];
        else          smeta_nch[i] = nchv[g];
    }
    {
        int pl = tid >> 6;            // wave writes its own pair's list
        int rest = tid & 63;
        int w2 = rest >> 4, e = (rest & 15) * 2;
        unsigned g = (p0 + pl) * 4 + w2;
        unsigned o = ofs[g];
        *(unsigned*)&slist[pl][w2][e] = *(const unsigned*)(lst + o + e);
    }

    i32x4 acc[8][2] = {};             // [m-frag 0..7][col-frag 0..1]

    // stage A window wdw into buffer buf (linear dest, XOR-pre-swizzled src)
    auto stage = [&](int wdw, int buf) {
#pragma unroll
        for (int i = 0; i < 8; ++i) {
            int f = i * 512 + tid;
            int row = f >> 5, g0 = f & 31;
            int src = (g0 & ~7) | ((g0 & 7) ^ (row & 7));
            async16((char*)lds.a[buf] + (size_t)f * 16,
                    A + (size_t)(m0 + row) * CIN + wdw * 512 + src * 16);
        }
    };

    // prologue: both buffers in flight; wait only buffer 0 (counted)
    stage(0, 0);
    stage(1, 1);
    asm volatile("s_waitcnt vmcnt(8) lgkmcnt(0)" ::: "memory");
    __builtin_amdgcn_s_barrier();

#pragma unroll
    for (int wdw = 0; wdw < NWIN; ++wdw) {
        const char* sa = (const char*)lds.a[wdw & 1];
        const unsigned o   = smeta_ofs[w * 4 + wdw];
        const unsigned nch = smeta_nch[w * 4 + wdw];
        const unsigned short* Lp = &slist[w][wdw][0];
        const char* bbase = Bc + (size_t)o * 512 + mrow * 16 + (size_t)kc * 512;

        if (nch) {
            // distance-1 pipeline: full next chunk (b0,b1) prefetched
            int   kkN = (int)Lp[kc];
            i32x4 b0N = *(const i32x4*)bbase;
            i32x4 b1N = *(const i32x4*)(bbase + 256);
            for (unsigned c = 0; c < nch; ++c) {
                const int   kkC = kkN;
                const i32x4 b0C = b0N, b1C = b1N;
                if (c + 1 < nch) {
                    kkN = (int)Lp[(c + 1) * 4 + kc];
                    b0N = *(const i32x4*)(bbase + (size_t)(c + 1) * 2048);
                    b1N = *(const i32x4*)(bbase + (size_t)(c + 1) * 2048 + 256);
                }
                const int swz = mrow * 512 + ((kkC ^ (mrow & 7)) << 4);
                i32x4 av[8];
#pragma unroll
                for (int mf = 0; mf < 8; ++mf)
                    av[mf] = *(const i32x4*)(sa + mf * 8192 + swz);
#pragma unroll
                for (int mf = 0; mf < 8; ++mf) {
                    acc[mf][0] = __builtin_amdgcn_mfma_i32_16x16x64_i8(
                        av[mf], b0C, acc[mf][0], 0, 0, 0);
                    acc[mf][1] = __builtin_amdgcn_mfma_i32_16x16x64_i8(
                        av[mf], b1C, acc[mf][1], 0, 0, 0);
                }
            }
        }

        __builtin_amdgcn_s_barrier();          // all waves done reading buf[wdw&1]
        if (wdw + 1 < NWIN) {
            if (wdw + 2 < NWIN) {
                stage(wdw + 2, wdw & 1);       // overwrite just-freed buffer
                // in-order retirement: stage(wdw+1) is older than compute(wdw)'s
                // consumed B loads -> already retired; this wait is ~free
                asm volatile("s_waitcnt vmcnt(8)" ::: "memory");
            } else {
                asm volatile("s_waitcnt vmcnt(0)" ::: "memory");
            }
            __builtin_amdgcn_s_barrier();      // stage(wdw+1) visible to all
        }
    }

    // ---- Epilogue: LIF scan, two passes of 128 channels ----
    const float thr = exp2f((float)thr_exp[0]);
#pragma unroll
    for (int P = 0; P < 2; ++P) {
        __syncthreads();
        if ((w >> 2) == P) {                   // waves 4P..4P+3 hold these cols
            const int rb = (lane >> 4) * 4;
            const int cb = lane & 15;
            const int cbase = (w & 3) * 32;
#pragma unroll
            for (int mf = 0; mf < 8; ++mf)
#pragma unroll
                for (int cf = 0; cf < 2; ++cf)
#pragma unroll
                    for (int r = 0; r < 4; ++r)
                        lds.c[(mf * 16 + rb + r) * 132 + cbase + cf * 16 + cb] =
                            (float)acc[mf][cf][r];
        }
        __syncthreads();

        if (tid < 128) {
            const float scale = exp2f((float)scale_exp[nt * 256 + P * 128 + tid]);
            float a = 0.f;
#pragma unroll
            for (int q = 0; q < 4; ++q) {
                unsigned bq = 0u;
#pragma unroll 8
                for (int j = 0; j < 32; ++j) {
                    a += lds.c[(q * 32 + j) * 132 + tid] * scale;
                    unsigned sp = (a >= thr) ? 1u : 0u;
                    if (sp) a = 0.f;
                    bq |= sp << j;
                }
                pb[tid * 4 + q] = bq;
            }
        }
        __syncthreads();

        const int t4 = tid & 31, u = tid >> 5;
#pragma unroll
        for (int s2 = 0; s2 < 8; ++s2) {
            int co = s2 * 16 + u;
            unsigned wb  = pb[co * 4 + (t4 >> 3)];
            unsigned nib = (wb >> ((t4 & 7) * 4)) & 0xFu;
            float4 v;
            v.x = (float)(nib & 1u);
            v.y = (float)((nib >> 1) & 1u);
            v.z = (float)((nib >> 2) & 1u);
            v.w = (float)((nib >> 3) & 1u);
            *(float4*)(out + (size_t)(b * COUT + nt * 256 + P * 128 + co) * TT
                       + t4 * 4) = v;
        }
    }
}

extern "C" void kernel_launch(void* const* d_in, const int* in_sizes, int n_in,
                              void* d_out, int out_size, void* d_ws, size_t ws_size,
                              hipStream_t stream) {
    const float* spikes  = (const float*)d_in[0];
    const float* weights = (const float*)d_in[1];
    const float* mask    = (const float*)d_in[2];
    const int*   scale_e = (const int*)d_in[3];
    const int*   thr_e   = (const int*)d_in[4];
    float* out = (float*)d_out;

    char* ws = (char*)d_ws;
    char*               Ai8  = ws;                                     // 16 MB
    char*               Bc   = ws + 16777216;                          // 3.75 MB arena
    unsigned short*     lstp = (unsigned short*)(ws + 20709376);       // 16 KB (incl slack)
    unsigned*           ofsp = (unsigned*)(ws + 20725760);             // 1 KB
    unsigned*           nchp = (unsigned*)(ws + 20726784);             // 1 KB
    unsigned long long* kbp  = (unsigned long long*)(ws + 20727808);   // 8 KB

    prep1<<<2048 + 256, 256, 0, stream>>>(spikes, mask, Ai8, kbp);
    prep2<<<NPAIR * NWIN, 256, 0, stream>>>(weights, mask, kbp, Bc, lstp, ofsp, nchp);
    snn_gemm_scan<<<8 * BB, 512, 0, stream>>>(Ai8, Bc, lstp, ofsp, nchp,
                                              scale_e, thr_e, out);
}